// Round 13
// baseline (181.424 us; speedup 1.0000x reference)
//
#include <hip/hip_runtime.h>
#include <hip/hip_fp16.h>

typedef unsigned short ushort_t;
typedef __attribute__((ext_vector_type(8))) _Float16 f16x8;
typedef __attribute__((ext_vector_type(2))) _Float16 f16v2;
typedef __attribute__((ext_vector_type(2))) __fp16 hw16x2;
typedef __attribute__((ext_vector_type(4))) float f32x4;

#define BB   2
#define CCH  256
#define HF   96
#define WF   320
#define NYC  7
#define DWT  16384
#define PLANE (HF*WF)          // 30720
#define KDIM (CCH*NYC)         // 1792
#define NKT  56                // K tiles of 32 (k = y*256 + c)
#define MBF  64                // positions per fused block
#define POS_TOTAL (BB*DWT)     // 32768

#define WH_BYTES   ((size_t)16*NKT*64*8*2)          // 917504
#define IITH_BYTES ((size_t)BB*PLANE*CCH*2)         // 31457280

// Av granule index (16B granules), row = (mt,kt,g) of 16 pos, padded 16->17
#define AV_G(mt,kt,g) ((((mt)*8+(kt))*4+(g))*17)

// ---------------- K1: fused integral image (rowcum + colcum) -----------------
__global__ __launch_bounds__(512)
void k_integral(const float* __restrict__ f, float* __restrict__ ii) {
    __shared__ float pl[PLANE];            // 122880 B
    int bc = blockIdx.x;
    const float* src = f  + (size_t)bc * PLANE;
    float*       dst = ii + (size_t)bc * PLANE;
    int t = threadIdx.x;

    #pragma unroll
    for (int i = 0; i < PLANE / 4 / 512; ++i) {
        int idx = t + i * 512;
        reinterpret_cast<float4*>(pl)[idx] = reinterpret_cast<const float4*>(src)[idx];
    }
    __syncthreads();

    int lane = t & 63, wv = t >> 6;
    for (int rr = 0; rr < 12; ++rr) {
        float* row = &pl[(wv * 12 + rr) * WF];
        float v0 = row[lane * 5 + 0];
        float v1 = row[lane * 5 + 1];
        float v2 = row[lane * 5 + 2];
        float v3 = row[lane * 5 + 3];
        float v4 = row[lane * 5 + 4];
        v1 += v0; v2 += v1; v3 += v2; v4 += v3;
        float s = v4;
        #pragma unroll
        for (int d = 1; d < 64; d <<= 1) {
            float o = __shfl_up(s, d);
            if (lane >= d) s += o;
        }
        float pre = s - v4;
        row[lane * 5 + 0] = v0 + pre;
        row[lane * 5 + 1] = v1 + pre;
        row[lane * 5 + 2] = v2 + pre;
        row[lane * 5 + 3] = v3 + pre;
        row[lane * 5 + 4] = v4 + pre;
    }
    __syncthreads();

    if (t < WF) {
        int x = t;
        float acc = 0.f;
        #pragma unroll 4
        for (int y = 0; y < HF; ++y) {
            acc += pl[y * WF + x];
            dst[(size_t)y * WF + x] = acc;
        }
    }
}

// ---------------- K2: transpose ii (B,C,H,W) f32 -> iith (B,H,W,C) fp16 ------
__global__ void k_transpose(const float* __restrict__ ii, _Float16* __restrict__ iith) {
    __shared__ float tile[32][33];
    int x0 = blockIdx.x * 32;
    int c0 = blockIdx.y * 32;
    int by = blockIdx.z;               // b*HF + y
    int b  = by / HF;
    int y  = by % HF;
    const float* src = ii + (size_t)b * CCH * PLANE + (size_t)y * WF;
    unsigned* dstu = reinterpret_cast<unsigned*>(iith + (size_t)by * WF * CCH);
    int tx = threadIdx.x;
    int ty = threadIdx.y;
    #pragma unroll
    for (int i = 0; i < 4; ++i) {
        int c = c0 + ty + 8 * i;
        tile[ty + 8 * i][tx] = src[(size_t)c * PLANE + x0 + tx];
    }
    __syncthreads();
    int id = ty * 32 + tx;
    #pragma unroll
    for (int it = 0; it < 2; ++it) {
        int idx = it * 256 + id;
        int xl = idx >> 4;
        int j  = idx & 15;
        float f0 = tile[2 * j][xl];
        float f1 = tile[2 * j + 1][xl];
        __half2 hh = __floats2half2_rn(f0, f1);
        dstu[((size_t)(x0 + xl) * CCH + c0) / 2 + j] = *reinterpret_cast<unsigned*>(&hh);
    }
}

// ---------------- K3: geometry -> g_tl, g_br, g_tr, g_bl ----------------
__global__ void k_geom(const float* __restrict__ calib, const float* __restrict__ grid,
                       float* __restrict__ gtl, float* __restrict__ gbr,
                       float* __restrict__ gtr, float* __restrict__ gbl) {
    int t = blockIdx.x * blockDim.x + threadIdx.x;
    if (t >= BB * NYC * DWT) return;
    int dw = t % DWT;
    int by = t / DWT;
    int y  = by % NYC;
    int b  = by / NYC;
    int d  = dw >> 7;
    int w  = dw & 127;
    const float* cb = calib + b * 12;

    float c0=cb[0],c1=cb[1],c2=cb[2],c3=cb[3];
    float c4=cb[4],c5=cb[5],c6=cb[6],c7=cb[7];
    float c8=cb[8],c9=cb[9],c10=cb[10],c11=cb[11];

    auto ncp = [&](int yy, int i, int j, float& ox, float& oy) {
        const float* g = grid + (((size_t)b * 129 + i) * 129 + j) * 3;
        float gx = g[0];
        float gy = g[1] + (0.5f * (float)yy - 2.0f);
        float gz = g[2];
        float h0 = c0*gx + c1*gy + c2*gz + c3;
        float h1 = c4*gx + c5*gy + c6*gz + c7;
        float h2 = c8*gx + c9*gy + c10*gz + c11;
        float ix = h0 / h2;
        float iy = h1 / h2;
        float nx = 2.0f * ix / ((float)WF / 0.125f) - 1.0f;
        float ny = 2.0f * iy / ((float)HF / 0.125f) - 1.0f;
        ox = fminf(fmaxf(nx, -1.f), 1.f);
        oy = fminf(fmaxf(ny, -1.f), 1.f);
    };

    float ax, ay, bx, byy, mx1, my1, mx2, my2;
    ncp(y,     d,     w,     ax,  ay);
    ncp(y,     d + 1, w,     bx,  byy);
    float minx = fminf(ax, bx), miny = fminf(ay, byy);
    ncp(y + 1, d + 1, w + 1, mx1, my1);
    ncp(y + 1, d,     w + 1, mx2, my2);
    float maxx = fmaxf(mx1, mx2), maxy = fmaxf(my1, my2);

    size_t o = (size_t)t * 2;
    gtl[o] = minx; gtl[o + 1] = miny;
    gbr[o] = maxx; gbr[o + 1] = maxy;
    gtr[o] = maxx; gtr[o + 1] = miny;
    gbl[o] = minx; gbl[o + 1] = maxy;
}

// ---------------- K4: prepack w -> fragment-linear f16 (k = y*256 + c) -------
__global__ void k_prepack(const float* __restrict__ w, _Float16* __restrict__ wh) {
    int t = blockIdx.x * blockDim.x + threadIdx.x;
    if (t >= 16 * NKT * 64) return;
    int lane = t & 63;
    int kt   = (t >> 6) % NKT;
    int nt   = t / (NKT * 64);
    int r = lane & 15, g = lane >> 4;
    const float* wr = w + (size_t)(nt * 16 + r) * KDIM;
    _Float16* dst = wh + (size_t)t * 8;
    #pragma unroll
    for (int j = 0; j < 8; ++j) {
        int k  = kt * 32 + g * 8 + j;
        int yy = k >> 8;
        int cc = k & 255;
        dst[j] = (_Float16)wr[cc * NYC + yy];
    }
}

// ---------------- K5: fused gather + MFMA GEMM, vox never leaves the CU ------
// 512 thr (8 waves), M=64 pos, N=256, K chunked by y (7 x 256).
// Per y: all waves gather chunk -> LDS Av (bank-padded), barrier, 64 MFMA/wave.
__global__ __launch_bounds__(512, 4)
void k_fused(const _Float16* __restrict__ iith, const _Float16* __restrict__ wh,
             const float* __restrict__ gtl, const float* __restrict__ gbr,
             const float* __restrict__ bias, float* __restrict__ ortho) {
    __shared__ f16x8 Av[4 * 8 * 4 * 17];       // 34816 B
    __shared__ int2  taps_s[2][MBF][17];       // 17408 B (q padded 16->17)
    __shared__ float inv_s[2][MBF];

    int t = threadIdx.x;
    int bid = blockIdx.x;
    int swz = (bid & 7) * (gridDim.x >> 3) + (bid >> 3);   // XCD-chunked (512%8==0)
    int pos0 = swz * MBF;
    int b   = pos0 / DWT;
    int dw0 = pos0 % DWT;

    int lane = t & 63, wv = t >> 6;
    int r = lane & 15, gq = lane >> 4;
    int mi = wv >> 2, ni = wv & 3;             // 2 m-groups x 4 n-groups
    int p   = t >> 3;                          // 0..63 (gather position)
    int oct = t & 7;                           // channel octet slot

    const _Float16* ibase = iith + (size_t)b * PLANE * CCH;

    // per-(thread) tap builder for slab y into buffer bf
    auto build_taps = [&](int y, int bf) {
        size_t gi = (((size_t)(b * NYC + y)) * DWT + dw0 + p) * 2;
        float g0 = gtl[gi], g1 = gtl[gi + 1];
        float g2 = gbr[gi], g3 = gbr[gi + 1];
        float area = (g2 - g0) * (g3 - g1) * ((float)HF * (float)WF * 0.25f) + 1e-6f;
        if (oct == 0) inv_s[bf][p] = (area > 1e-6f) ? (1.0f / area) : 0.0f;
        const float pxs[4] = {g0, g2, g2, g0};
        const float pys[4] = {g1, g3, g1, g3};
        #pragma unroll
        for (int qq = 0; qq < 2; ++qq) {
            int q = oct * 2 + qq;
            int corner = q >> 2, s = q & 3;
            float sg = (corner < 2) ? 1.f : -1.f;
            float x  = (pxs[corner] + 1.0f) * ((float)WF * 0.5f) - 0.5f;
            float yy = (pys[corner] + 1.0f) * ((float)HF * 0.5f) - 0.5f;
            float x0f = floorf(x), y0f = floorf(yy);
            float wx = x - x0f, wy = yy - y0f;
            float wq = ((s & 1) ? wx : 1.f - wx) * ((s >> 1) ? wy : 1.f - wy);
            float xi = x0f + (float)(s & 1);
            float yi = y0f + (float)(s >> 1);
            bool valid = (xi >= 0.f) && (xi < (float)WF) && (yi >= 0.f) && (yi < (float)HF);
            int xc = (int)fminf(fmaxf(xi, 0.f), (float)(WF - 1));
            int yc = (int)fminf(fmaxf(yi, 0.f), (float)(HF - 1));
            float wgt = valid ? (wq * sg) : 0.0f;
            hw16x2 hw = __builtin_amdgcn_cvt_pkrtz(wgt, wgt);
            taps_s[bf][p][q] = make_int2((yc * WF + xc) * CCH, *reinterpret_cast<int*>(&hw));
        }
    };

    // B fragment pointers for this wave's 4 n-tiles
    const f16x8* bp0 = reinterpret_cast<const f16x8*>(wh) + ((size_t)(ni * 4 + 0) * NKT) * 64 + lane;
    const f16x8* bp1 = reinterpret_cast<const f16x8*>(wh) + ((size_t)(ni * 4 + 1) * NKT) * 64 + lane;
    const f16x8* bp2 = reinterpret_cast<const f16x8*>(wh) + ((size_t)(ni * 4 + 2) * NKT) * 64 + lane;
    const f16x8* bp3 = reinterpret_cast<const f16x8*>(wh) + ((size_t)(ni * 4 + 3) * NKT) * 64 + lane;

    f32x4 acc[2][4] = {};

    build_taps(0, 0);
    __syncthreads();

    for (int y = 0; y < NYC; ++y) {
        int bf = y & 1;
        // ---- sample phase: gather this y's 64pos x 256ch chunk into Av ----
        {
            const int2* tps = taps_s[bf][p];
            float inv = inv_s[bf][p];
            hw16x2 ivh = __builtin_amdgcn_cvt_pkrtz(inv, inv);
            f16v2 iv2 = *reinterpret_cast<f16v2*>(&ivh);
            int2 tp[16];
            #pragma unroll
            for (int q = 0; q < 16; ++q) tp[q] = tps[q];
            int mt = p >> 4, pr = p & 15, g = oct & 3;
            #pragma unroll
            for (int rep = 0; rep < 4; ++rep) {
                int c = rep * 64 + oct * 8;
                f16v2 a0 = {0,0}, a1 = {0,0}, a2 = {0,0}, a3 = {0,0};
                #pragma unroll
                for (int q = 0; q < 16; ++q) {
                    f16v2 w2 = *reinterpret_cast<f16v2*>(&tp[q].y);
                    uint4 hv = *reinterpret_cast<const uint4*>(ibase + tp[q].x + c);
                    a0 += w2 * *reinterpret_cast<f16v2*>(&hv.x);
                    a1 += w2 * *reinterpret_cast<f16v2*>(&hv.y);
                    a2 += w2 * *reinterpret_cast<f16v2*>(&hv.z);
                    a3 += w2 * *reinterpret_cast<f16v2*>(&hv.w);
                }
                a0 *= iv2; a1 *= iv2; a2 *= iv2; a3 *= iv2;
                f16x8 o;
                o[0] = a0[0]; o[1] = a0[1]; o[2] = a1[0]; o[3] = a1[1];
                o[4] = a2[0]; o[5] = a2[1]; o[6] = a3[0]; o[7] = a3[1];
                int kt = rep * 2 + (oct >> 2);
                Av[AV_G(mt, kt, g) + pr] = o;
            }
        }
        __syncthreads();

        // ---- build next y's taps (overlaps gemm's MFMA with its loads) ----
        if (y + 1 < NYC) build_taps(y + 1, bf ^ 1);

        // ---- gemm phase: 8 k-tiles of this chunk ----
        {
            int ktg0 = y * 8;
            #pragma unroll
            for (int ktl = 0; ktl < 8; ++ktl) {
                f16x8 a0 = Av[AV_G(mi * 2,     ktl, gq) + r];
                f16x8 a1 = Av[AV_G(mi * 2 + 1, ktl, gq) + r];
                size_t ko = (size_t)(ktg0 + ktl) * 64;
                f16x8 b0 = bp0[ko], b1 = bp1[ko], b2 = bp2[ko], b3 = bp3[ko];
                acc[0][0] = __builtin_amdgcn_mfma_f32_16x16x32_f16(a0, b0, acc[0][0], 0, 0, 0);
                acc[1][0] = __builtin_amdgcn_mfma_f32_16x16x32_f16(a1, b0, acc[1][0], 0, 0, 0);
                acc[0][1] = __builtin_amdgcn_mfma_f32_16x16x32_f16(a0, b1, acc[0][1], 0, 0, 0);
                acc[1][1] = __builtin_amdgcn_mfma_f32_16x16x32_f16(a1, b1, acc[1][1], 0, 0, 0);
                acc[0][2] = __builtin_amdgcn_mfma_f32_16x16x32_f16(a0, b2, acc[0][2], 0, 0, 0);
                acc[1][2] = __builtin_amdgcn_mfma_f32_16x16x32_f16(a1, b2, acc[1][2], 0, 0, 0);
                acc[0][3] = __builtin_amdgcn_mfma_f32_16x16x32_f16(a0, b3, acc[0][3], 0, 0, 0);
                acc[1][3] = __builtin_amdgcn_mfma_f32_16x16x32_f16(a1, b3, acc[1][3], 0, 0, 0);
            }
        }
        __syncthreads();   // Av free for next sample
    }

    // ---- epilogue: bias + relu + float4 stores ----
    #pragma unroll
    for (int nn = 0; nn < 4; ++nn) {
        int co = (ni * 4 + nn) * 16 + r;
        float bv = bias[co];
        float* ob = ortho + ((size_t)(b * CCH + co)) * DWT + dw0 + gq * 4;
        #pragma unroll
        for (int mm = 0; mm < 2; ++mm) {
            f32x4 a = acc[mm][nn];
            float4 o = make_float4(fmaxf(a[0] + bv, 0.f), fmaxf(a[1] + bv, 0.f),
                                   fmaxf(a[2] + bv, 0.f), fmaxf(a[3] + bv, 0.f));
            *reinterpret_cast<float4*>(ob + (mi * 2 + mm) * 16) = o;
        }
    }
}

extern "C" void kernel_launch(void* const* d_in, const int* in_sizes, int n_in,
                              void* d_out, int out_size, void* d_ws, size_t ws_size,
                              hipStream_t stream) {
    const float* features = (const float*)d_in[0];
    const float* calib    = (const float*)d_in[1];
    const float* grid     = (const float*)d_in[2];
    const float* w        = (const float*)d_in[3];
    const float* bias     = (const float*)d_in[4];

    float* out   = (float*)d_out;
    float* ortho = out;
    float* ii    = out + (size_t)8388608;
    float* gtl   = out + (size_t)24117248;
    float* gbr   = out + (size_t)24576000;
    float* gtr   = out + (size_t)25034752;
    float* gbl   = out + (size_t)25493504;

    _Float16* wh   = (_Float16*)d_ws;
    _Float16* iith = (_Float16*)((char*)d_ws + WH_BYTES);

    k_integral<<<BB * CCH, 512, 0, stream>>>(features, ii);
    k_geom    <<<(BB * NYC * DWT + 255) / 256, 256, 0, stream>>>(calib, grid, gtl, gbr, gtr, gbl);
    k_prepack <<<(16 * NKT * 64 + 255) / 256, 256, 0, stream>>>(w, wh);
    dim3 gT(WF / 32, CCH / 32, BB * HF);
    k_transpose<<<gT, dim3(32, 8), 0, stream>>>(ii, iith);

    k_fused<<<POS_TOTAL / MBF, 512, 0, stream>>>(iith, wh, gtl, gbr, bias, ortho);
}

// Round 14
// 175.595 us; speedup vs baseline: 1.0332x; 1.0332x over previous
//
#include <hip/hip_runtime.h>
#include <hip/hip_fp16.h>

typedef unsigned short ushort_t;
typedef __attribute__((ext_vector_type(8))) _Float16 f16x8;
typedef __attribute__((ext_vector_type(2))) _Float16 f16v2;
typedef __attribute__((ext_vector_type(2))) __fp16 hw16x2;
typedef __attribute__((ext_vector_type(4))) float f32x4;

#define BB   2
#define CCH  256
#define HF   96
#define WF   320
#define NYC  7
#define DWT  16384
#define PLANE (HF*WF)          // 30720
#define KDIM (CCH*NYC)         // 1792
#define NKT  56                // K tiles of 32 (k = y*256 + c)
#define MS   8                 // positions per sample block
#define POS_TOTAL (BB*DWT)     // 32768

#define WH_BYTES   ((size_t)16*NKT*64*8*2)          // 917504
#define IITH_BYTES ((size_t)BB*PLANE*CCH*2)         // 31457280

// ---------------- K1: fused integral image (rowcum + colcum) -----------------
__global__ __launch_bounds__(512)
void k_integral(const float* __restrict__ f, float* __restrict__ ii) {
    __shared__ float pl[PLANE];            // 122880 B
    int bc = blockIdx.x;
    const float* src = f  + (size_t)bc * PLANE;
    float*       dst = ii + (size_t)bc * PLANE;
    int t = threadIdx.x;

    #pragma unroll
    for (int i = 0; i < PLANE / 4 / 512; ++i) {
        int idx = t + i * 512;
        reinterpret_cast<float4*>(pl)[idx] = reinterpret_cast<const float4*>(src)[idx];
    }
    __syncthreads();

    int lane = t & 63, wv = t >> 6;
    for (int rr = 0; rr < 12; ++rr) {
        float* row = &pl[(wv * 12 + rr) * WF];
        float v0 = row[lane * 5 + 0];
        float v1 = row[lane * 5 + 1];
        float v2 = row[lane * 5 + 2];
        float v3 = row[lane * 5 + 3];
        float v4 = row[lane * 5 + 4];
        v1 += v0; v2 += v1; v3 += v2; v4 += v3;
        float s = v4;
        #pragma unroll
        for (int d = 1; d < 64; d <<= 1) {
            float o = __shfl_up(s, d);
            if (lane >= d) s += o;
        }
        float pre = s - v4;
        row[lane * 5 + 0] = v0 + pre;
        row[lane * 5 + 1] = v1 + pre;
        row[lane * 5 + 2] = v2 + pre;
        row[lane * 5 + 3] = v3 + pre;
        row[lane * 5 + 4] = v4 + pre;
    }
    __syncthreads();

    if (t < WF) {
        int x = t;
        float acc = 0.f;
        #pragma unroll 4
        for (int y = 0; y < HF; ++y) {
            acc += pl[y * WF + x];
            dst[(size_t)y * WF + x] = acc;
        }
    }
}

// ---------------- K2: transpose ii (B,C,H,W) f32 -> iith (B,H,W,C) fp16 ------
__global__ void k_transpose(const float* __restrict__ ii, _Float16* __restrict__ iith) {
    __shared__ float tile[32][33];
    int x0 = blockIdx.x * 32;
    int c0 = blockIdx.y * 32;
    int by = blockIdx.z;               // b*HF + y
    int b  = by / HF;
    int y  = by % HF;
    const float* src = ii + (size_t)b * CCH * PLANE + (size_t)y * WF;
    unsigned* dstu = reinterpret_cast<unsigned*>(iith + (size_t)by * WF * CCH);
    int tx = threadIdx.x;
    int ty = threadIdx.y;
    #pragma unroll
    for (int i = 0; i < 4; ++i) {
        int c = c0 + ty + 8 * i;
        tile[ty + 8 * i][tx] = src[(size_t)c * PLANE + x0 + tx];
    }
    __syncthreads();
    int id = ty * 32 + tx;
    #pragma unroll
    for (int it = 0; it < 2; ++it) {
        int idx = it * 256 + id;
        int xl = idx >> 4;
        int j  = idx & 15;
        float f0 = tile[2 * j][xl];
        float f1 = tile[2 * j + 1][xl];
        __half2 hh = __floats2half2_rn(f0, f1);
        dstu[((size_t)(x0 + xl) * CCH + c0) / 2 + j] = *reinterpret_cast<unsigned*>(&hh);
    }
}

// ---------------- K3: geometry -> g_tl, g_br, g_tr, g_bl ----------------
__global__ void k_geom(const float* __restrict__ calib, const float* __restrict__ grid,
                       float* __restrict__ gtl, float* __restrict__ gbr,
                       float* __restrict__ gtr, float* __restrict__ gbl) {
    int t = blockIdx.x * blockDim.x + threadIdx.x;
    if (t >= BB * NYC * DWT) return;
    int dw = t % DWT;
    int by = t / DWT;
    int y  = by % NYC;
    int b  = by / NYC;
    int d  = dw >> 7;
    int w  = dw & 127;
    const float* cb = calib + b * 12;

    float c0=cb[0],c1=cb[1],c2=cb[2],c3=cb[3];
    float c4=cb[4],c5=cb[5],c6=cb[6],c7=cb[7];
    float c8=cb[8],c9=cb[9],c10=cb[10],c11=cb[11];

    auto ncp = [&](int yy, int i, int j, float& ox, float& oy) {
        const float* g = grid + (((size_t)b * 129 + i) * 129 + j) * 3;
        float gx = g[0];
        float gy = g[1] + (0.5f * (float)yy - 2.0f);
        float gz = g[2];
        float h0 = c0*gx + c1*gy + c2*gz + c3;
        float h1 = c4*gx + c5*gy + c6*gz + c7;
        float h2 = c8*gx + c9*gy + c10*gz + c11;
        float ix = h0 / h2;
        float iy = h1 / h2;
        float nx = 2.0f * ix / ((float)WF / 0.125f) - 1.0f;
        float ny = 2.0f * iy / ((float)HF / 0.125f) - 1.0f;
        ox = fminf(fmaxf(nx, -1.f), 1.f);
        oy = fminf(fmaxf(ny, -1.f), 1.f);
    };

    float ax, ay, bx, byy, mx1, my1, mx2, my2;
    ncp(y,     d,     w,     ax,  ay);
    ncp(y,     d + 1, w,     bx,  byy);
    float minx = fminf(ax, bx), miny = fminf(ay, byy);
    ncp(y + 1, d + 1, w + 1, mx1, my1);
    ncp(y + 1, d,     w + 1, mx2, my2);
    float maxx = fmaxf(mx1, mx2), maxy = fmaxf(my1, my2);

    size_t o = (size_t)t * 2;
    gtl[o] = minx; gtl[o + 1] = miny;
    gbr[o] = maxx; gbr[o + 1] = maxy;
    gtr[o] = maxx; gtr[o + 1] = miny;
    gbl[o] = minx; gbl[o + 1] = maxy;
}

// ---------------- K4: prepack w -> fragment-linear f16 (k = y*256 + c) -------
__global__ void k_prepack(const float* __restrict__ w, _Float16* __restrict__ wh) {
    int t = blockIdx.x * blockDim.x + threadIdx.x;
    if (t >= 16 * NKT * 64) return;
    int lane = t & 63;
    int kt   = (t >> 6) % NKT;
    int nt   = t / (NKT * 64);
    int r = lane & 15, g = lane >> 4;
    const float* wr = w + (size_t)(nt * 16 + r) * KDIM;
    _Float16* dst = wh + (size_t)t * 8;
    #pragma unroll
    for (int j = 0; j < 8; ++j) {
        int k  = kt * 32 + g * 8 + j;
        int yy = k >> 8;
        int cc = k & 255;
        dst[j] = (_Float16)wr[cc * NYC + yy];
    }
}

// ---------------- K5: pure gather -> vox fragments (f16, forced MLP=16) ------
// thread: p = t>>5 (8 positions/block), c = (t&31)*8 (channel octet)
// sched_barrier(0) pins all 16 tap loads BEFORE any FMA -> 16 loads in flight.
__global__ __launch_bounds__(256, 4)
void k_sample(const _Float16* __restrict__ iith, const float* __restrict__ gtl,
              const float* __restrict__ gbr, _Float16* __restrict__ voxf, int pos_base) {
    __shared__ int2 taps[MS][NYC][17];       // 17-pad
    __shared__ float inv_s[MS][NYC + 1];
    int t = threadIdx.x;
    int bid = blockIdx.x;
    int cpx = gridDim.x >> 3;
    int swz = (bid & 7) * cpx + (bid >> 3);  // XCD-chunked (grid % 8 == 0)
    int lpos0 = swz * MS;
    int pos0  = pos_base + lpos0;
    int b   = pos0 / DWT;
    int dw0 = pos0 % DWT;

    if (t < MS * NYC) {
        int p = t / NYC, y = t % NYC;
        size_t gi = (((size_t)(b * NYC + y)) * DWT + dw0 + p) * 2;
        float g0 = gtl[gi], g1 = gtl[gi + 1];
        float g2 = gbr[gi], g3 = gbr[gi + 1];
        float area = (g2 - g0) * (g3 - g1) * ((float)HF * (float)WF * 0.25f) + 1e-6f;
        inv_s[p][y] = (area > 1e-6f) ? (1.0f / area) : 0.0f;
        const float sgn[4] = {1.f, 1.f, -1.f, -1.f};
        float px[4] = {g0, g2, g2, g0};
        float py[4] = {g1, g3, g1, g3};
        #pragma unroll
        for (int q = 0; q < 4; ++q) {
            float x  = (px[q] + 1.0f) * ((float)WF * 0.5f) - 0.5f;
            float yy = (py[q] + 1.0f) * ((float)HF * 0.5f) - 0.5f;
            float x0f = floorf(x), y0f = floorf(yy);
            float wx = x - x0f, wy = yy - y0f;
            float wq[4] = {(1.f-wx)*(1.f-wy), wx*(1.f-wy), (1.f-wx)*wy, wx*wy};
            #pragma unroll
            for (int s = 0; s < 4; ++s) {
                float xi = x0f + (float)(s & 1);
                float yi = y0f + (float)(s >> 1);
                bool valid = (xi >= 0.f) && (xi < (float)WF) && (yi >= 0.f) && (yi < (float)HF);
                int xc = (int)fminf(fmaxf(xi, 0.f), (float)(WF - 1));
                int yc = (int)fminf(fmaxf(yi, 0.f), (float)(HF - 1));
                float wgt = valid ? (wq[s] * sgn[q]) : 0.0f;
                hw16x2 hw = __builtin_amdgcn_cvt_pkrtz(wgt, wgt);
                taps[p][y][q * 4 + s] =
                    make_int2((yc * WF + xc) * CCH, *reinterpret_cast<int*>(&hw));
            }
        }
    }
    __syncthreads();

    int p = t >> 5;
    int c = (t & 31) * 8;
    int lpos = lpos0 + p;
    int mt = lpos >> 4, r = lpos & 15, g = (c >> 3) & 3;
    const _Float16* base = iith + (size_t)b * PLANE * CCH + c;
    _Float16* vbase = voxf + ((size_t)mt * NKT * 64 + (size_t)(g * 16 + r)) * 8;

    for (int y = 0; y < NYC; ++y) {
        int2 tp[16];
        #pragma unroll
        for (int q = 0; q < 16; ++q) tp[q] = taps[p][y][q];

        // issue ALL 16 tap loads, then fence the scheduler: no FMA may be
        // hoisted between them -> all 16 stay in flight (MLP=16)
        uint4 hv[16];
        #pragma unroll
        for (int q = 0; q < 16; ++q)
            hv[q] = *reinterpret_cast<const uint4*>(base + tp[q].x);
        __builtin_amdgcn_sched_barrier(0);

        f16v2 a0 = {0, 0}, a1 = {0, 0}, a2 = {0, 0}, a3 = {0, 0};
        #pragma unroll
        for (int q = 0; q < 16; ++q) {
            f16v2 w2 = *reinterpret_cast<f16v2*>(&tp[q].y);
            a0 += w2 * *reinterpret_cast<f16v2*>(&hv[q].x);
            a1 += w2 * *reinterpret_cast<f16v2*>(&hv[q].y);
            a2 += w2 * *reinterpret_cast<f16v2*>(&hv[q].z);
            a3 += w2 * *reinterpret_cast<f16v2*>(&hv[q].w);
        }
        float inv = inv_s[p][y];
        hw16x2 ivh = __builtin_amdgcn_cvt_pkrtz(inv, inv);
        f16v2 iv2 = *reinterpret_cast<f16v2*>(&ivh);
        a0 *= iv2; a1 *= iv2; a2 *= iv2; a3 *= iv2;

        int kt = (y << 3) + (c >> 5);
        f16x8 o;
        o[0] = a0[0]; o[1] = a0[1]; o[2] = a1[0]; o[3] = a1[1];
        o[4] = a2[0]; o[5] = a2[1]; o[6] = a3[0]; o[7] = a3[1];
        // normal cached store (r10: nontemporal doubles HBM writes)
        *reinterpret_cast<f16x8*>(vbase + (size_t)kt * 64 * 8) = o;
    }
}

// ---------------- K6: register-blocked MFMA GEMM (128M x 128N per block) -----
// r8 config (best measured): 4 waves 2x2; wave tile mA=4 x nB=4; depth-2 dbuf
__global__ __launch_bounds__(256)
void k_gemm(const _Float16* __restrict__ voxf, const _Float16* __restrict__ wh,
            const float* __restrict__ bias, float* __restrict__ ortho, int pos_base) {
    int t = threadIdx.x;
    int lane = t & 63, wv = t >> 6;
    int mi = wv >> 1, ni = wv & 1;
    int bx = blockIdx.x;
    int swz = (bx & 7) * (gridDim.x >> 3) + (bx >> 3);   // XCD-chunked
    int nhalf = swz & 1, pm = swz >> 1;
    int lpos0 = pm * 128;
    int pos0 = pos_base + lpos0;
    int b = pos0 / DWT, dw0 = pos0 % DWT;
    int mt0 = (lpos0 >> 4) + mi * 4;
    int nt0 = nhalf * 8 + ni * 4;

    const f16x8* ap = reinterpret_cast<const f16x8*>(voxf) + (size_t)mt0 * NKT * 64 + lane;
    const f16x8* bp = reinterpret_cast<const f16x8*>(wh)   + (size_t)nt0 * NKT * 64 + lane;
    const size_t TS = (size_t)NKT * 64;     // tile stride in f16x8

    f32x4 acc[4][4] = {};
    f16x8 A0[4], B0[4], A1[4], B1[4];
    #pragma unroll
    for (int i = 0; i < 4; ++i) {
        A0[i] = ap[i * TS];
        B0[i] = bp[i * TS];
        A1[i] = ap[i * TS + 64];
        B1[i] = bp[i * TS + 64];
    }

    for (int kt = 0; kt < NKT; kt += 2) {
        #pragma unroll
        for (int m = 0; m < 4; ++m)
            #pragma unroll
            for (int n = 0; n < 4; ++n)
                acc[m][n] = __builtin_amdgcn_mfma_f32_16x16x32_f16(A0[m], B0[n], acc[m][n], 0, 0, 0);
        if (kt + 2 < NKT) {
            #pragma unroll
            for (int i = 0; i < 4; ++i) {
                A0[i] = ap[i * TS + (size_t)(kt + 2) * 64];
                B0[i] = bp[i * TS + (size_t)(kt + 2) * 64];
            }
        }
        #pragma unroll
        for (int m = 0; m < 4; ++m)
            #pragma unroll
            for (int n = 0; n < 4; ++n)
                acc[m][n] = __builtin_amdgcn_mfma_f32_16x16x32_f16(A1[m], B1[n], acc[m][n], 0, 0, 0);
        if (kt + 3 < NKT) {
            #pragma unroll
            for (int i = 0; i < 4; ++i) {
                A1[i] = ap[i * TS + (size_t)(kt + 3) * 64];
                B1[i] = bp[i * TS + (size_t)(kt + 3) * 64];
            }
        }
    }

    int r = lane & 15, gq = lane >> 4;
    #pragma unroll
    for (int n = 0; n < 4; ++n) {
        int co = nhalf * 128 + (ni * 4 + n) * 16 + r;
        float bv = bias[co];
        float* ob = ortho + ((size_t)(b * CCH + co)) * DWT + dw0 + gq * 4;
        #pragma unroll
        for (int m = 0; m < 4; ++m) {
            float4 o = make_float4(fmaxf(acc[m][n][0] + bv, 0.f), fmaxf(acc[m][n][1] + bv, 0.f),
                                   fmaxf(acc[m][n][2] + bv, 0.f), fmaxf(acc[m][n][3] + bv, 0.f));
            *reinterpret_cast<float4*>(ob + (mi * 4 + m) * 16) = o;
        }
    }
}

extern "C" void kernel_launch(void* const* d_in, const int* in_sizes, int n_in,
                              void* d_out, int out_size, void* d_ws, size_t ws_size,
                              hipStream_t stream) {
    const float* features = (const float*)d_in[0];
    const float* calib    = (const float*)d_in[1];
    const float* grid     = (const float*)d_in[2];
    const float* w        = (const float*)d_in[3];
    const float* bias     = (const float*)d_in[4];

    float* out   = (float*)d_out;
    float* ortho = out;
    float* ii    = out + (size_t)8388608;
    float* gtl   = out + (size_t)24117248;
    float* gbr   = out + (size_t)24576000;
    float* gtr   = out + (size_t)25034752;
    float* gbl   = out + (size_t)25493504;

    _Float16* wh   = (_Float16*)d_ws;
    _Float16* iith = (_Float16*)((char*)d_ws + WH_BYTES);
    _Float16* voxf = (_Float16*)((char*)d_ws + WH_BYTES + IITH_BYTES);

    k_integral<<<BB * CCH, 512, 0, stream>>>(features, ii);
    k_geom    <<<(BB * NYC * DWT + 255) / 256, 256, 0, stream>>>(calib, grid, gtl, gbr, gtr, gbl);
    k_prepack <<<(16 * NKT * 64 + 255) / 256, 256, 0, stream>>>(w, wh);
    dim3 gT(WF / 32, CCH / 32, BB * HF);
    k_transpose<<<gT, dim3(32, 8), 0, stream>>>(ii, iith);

    // nch=1 when ws fits the full vox (117 MB)
    size_t vox_all = (size_t)POS_TOTAL * KDIM * 2;
    int nch = (ws_size >= WH_BYTES + IITH_BYTES + vox_all) ? 1 : 4;
    int cpos = POS_TOTAL / nch;
    for (int cidx = 0; cidx < nch; ++cidx) {
        int pb = cidx * cpos;
        k_sample<<<cpos / MS, 256, 0, stream>>>(iith, gtl, gbr, voxf, pb);
        k_gemm  <<<(cpos / 128) * 2, 256, 0, stream>>>(voxf, wh, bias, ortho, pb);
    }
}